// Round 1
// baseline (317.910 us; speedup 1.0000x reference)
//
#include <hip/hip_runtime.h>

#define NJ   17
#define FD   128
#define NC   128
#define NNZ  49
#define FPB  4    // frames per block

// ---------------------------------------------------------------------------
// Kernel 1: adjacency softmax prep.
// Softmax over a row filled with -9e15 except at nnz entries == exp(e)/sum(exp(e))
// over just that row's entries (exp(NEG-max) underflows to exactly 0 in f32).
// Entries are sorted by row (np.nonzero row-major), so rows are contiguous.
// Outputs: wnorm[k][c] (layout [NNZ][NC], c fastest) and row_ptr[NJ+1].
// ---------------------------------------------------------------------------
__global__ void prep_kernel(const float* __restrict__ e,
                            const int*   __restrict__ ii,
                            float*       __restrict__ wnorm,
                            int*         __restrict__ rp_out) {
  __shared__ int rp[NJ + 1];
  const int tid = threadIdx.x;
  if (tid == 0) {
    int pos = 0;
    for (int j = 0; j <= NJ; ++j) {
      while (pos < NNZ && ii[pos] < j) ++pos;   // ii ascending
      rp[j] = pos;
      rp_out[j] = pos;
    }
  }
  __syncthreads();
  const int c = tid;  // 128 threads, one channel each
  for (int j = 0; j < NJ; ++j) {
    const int k0 = rp[j], k1 = rp[j + 1];
    float m = -1e30f;
    for (int k = k0; k < k1; ++k) m = fmaxf(m, e[c * NNZ + k]);
    float s = 0.0f;
    for (int k = k0; k < k1; ++k) s += expf(e[c * NNZ + k] - m);
    const float inv = 1.0f / s;
    for (int k = k0; k < k1; ++k) wnorm[k * NC + c] = expf(e[c * NNZ + k] - m) * inv;
  }
}

// ---------------------------------------------------------------------------
// Kernel 2: fused GEMM (h0,h1) + per-channel adjacency aggregation.
// 256 threads = 4 waves; wave f owns frame blockIdx.x*4+f.
// Within a wave: lanes 0-31 compute h0, lanes 32-63 compute h1 (wsel),
// each lane a 4-channel quad (c0). acc[17][4] = h for all 17 joints.
// x addresses are wave-uniform (readfirstlane'd frame) -> scalar loads.
// Only h1 round-trips through LDS; h0's diag term stays in registers.
// ---------------------------------------------------------------------------
__global__ __launch_bounds__(256, 4) void fused_kernel(
    const float* __restrict__ x,
    const float* __restrict__ W,
    const float* __restrict__ wnorm,
    const int*   __restrict__ rp,
    const int*   __restrict__ idxj,
    float*       __restrict__ out) {
  __shared__ __align__(16) float hs[FPB][NJ][FD];  // h1 per frame

  const int tid  = threadIdx.x;
  const int f    = tid >> 6;          // wave index = local frame
  const int wsel = (tid >> 5) & 1;    // 0: W0/h0, 1: W1/h1
  const int c0   = (tid & 31) * 4;    // channel quad
  const int frame = blockIdx.x * FPB + f;
  const int fu = __builtin_amdgcn_readfirstlane(frame);

  const float* __restrict__ xf = x + (size_t)fu * (NJ * FD);  // wave-uniform
  const float* __restrict__ Wp = W + (size_t)wsel * (FD * NC);

  float acc[NJ][4];
#pragma unroll
  for (int j = 0; j < NJ; ++j) {
    acc[j][0] = 0.f; acc[j][1] = 0.f; acc[j][2] = 0.f; acc[j][3] = 0.f;
  }

#pragma unroll 1
  for (int i0 = 0; i0 < FD; i0 += 4) {
    const float4 w0 = *(const float4*)(Wp + (i0 + 0) * NC + c0);
    const float4 w1 = *(const float4*)(Wp + (i0 + 1) * NC + c0);
    const float4 w2 = *(const float4*)(Wp + (i0 + 2) * NC + c0);
    const float4 w3 = *(const float4*)(Wp + (i0 + 3) * NC + c0);
#pragma unroll
    for (int j = 0; j < NJ; ++j) {
      const float4 xv = *(const float4*)(xf + j * FD + i0);  // uniform -> s_load
      acc[j][0] += xv.x * w0.x + xv.y * w1.x + xv.z * w2.x + xv.w * w3.x;
      acc[j][1] += xv.x * w0.y + xv.y * w1.y + xv.z * w2.y + xv.w * w3.y;
      acc[j][2] += xv.x * w0.z + xv.y * w1.z + xv.z * w2.z + xv.w * w3.z;
      acc[j][3] += xv.x * w0.w + xv.y * w1.w + xv.z * w2.w + xv.w * w3.w;
    }
  }

  // stash h1 in LDS
  if (wsel) {
#pragma unroll
    for (int j = 0; j < NJ; ++j) {
      *(float4*)&hs[f][j][c0] =
          make_float4(acc[j][0], acc[j][1], acc[j][2], acc[j][3]);
    }
  }
  __syncthreads();

  // aggregation: out[j,c] = w_diag*h0[j,c] + sum_offdiag w*h1[col,c]
  if (!wsel) {
    float* __restrict__ op = out + (size_t)frame * (NJ * NC);
#pragma unroll
    for (int j = 0; j < NJ; ++j) {
      float4 o = make_float4(0.f, 0.f, 0.f, 0.f);
      const int k0 = rp[j], k1 = rp[j + 1];
      for (int k = k0; k < k1; ++k) {
        const int col = idxj[k];
        const float4 wk = *(const float4*)(wnorm + k * NC + c0);
        float4 hv;
        if (col == j) {
          hv = make_float4(acc[j][0], acc[j][1], acc[j][2], acc[j][3]);
        } else {
          hv = *(const float4*)&hs[f][col][c0];
        }
        o.x += wk.x * hv.x; o.y += wk.y * hv.y;
        o.z += wk.z * hv.z; o.w += wk.w * hv.w;
      }
      *(float4*)(op + j * NC + c0) = o;
    }
  }
}

// ---------------------------------------------------------------------------
extern "C" void kernel_launch(void* const* d_in, const int* in_sizes, int n_in,
                              void* d_out, int out_size, void* d_ws, size_t ws_size,
                              hipStream_t stream) {
  const float* x  = (const float*)d_in[0];  // [B,T,J,F]
  const float* W  = (const float*)d_in[1];  // [2,F,C]
  const float* e  = (const float*)d_in[2];  // [C,NNZ]
  const int*   ii = (const int*)d_in[3];    // [NNZ]
  const int*   jj = (const int*)d_in[4];    // [NNZ]
  float* out = (float*)d_out;

  float* wnorm = (float*)d_ws;                                 // [NNZ][NC]
  int*   rp    = (int*)((char*)d_ws + NNZ * NC * sizeof(float)); // [NJ+1]

  prep_kernel<<<1, NC, 0, stream>>>(e, ii, wnorm, rp);

  const int frames = in_sizes[0] / (NJ * FD);   // 15552
  const int blocks = frames / FPB;              // 3888
  fused_kernel<<<blocks, 256, 0, stream>>>(x, W, wnorm, rp, jj, out);
}

// Round 2
// 174.987 us; speedup vs baseline: 1.8168x; 1.8168x over previous
//
#include <hip/hip_runtime.h>

#define NJ   17
#define FD   128
#define NC   128
#define NNZ  49
#define FR   4            // frames per block
#define RPB  (FR * NJ)    // 68 rows per block

typedef __attribute__((ext_vector_type(8))) short bf16x8;   // 8 bf16 (4 VGPR)
typedef __attribute__((ext_vector_type(4))) float f32x4;

__device__ __forceinline__ ushort f2bf(float f) {   // f32 -> bf16 RNE
  unsigned u = __float_as_uint(f);
  u = (u + 0x7fffu + ((u >> 16) & 1u)) >> 16;
  return (ushort)u;
}
__device__ __forceinline__ float bf2f(ushort s) {
  return __uint_as_float(((unsigned)s) << 16);
}

// ---------------------------------------------------------------------------
// Kernel 1: adjacency softmax prep (unchanged from validated round 1).
// ---------------------------------------------------------------------------
__global__ void prep_kernel(const float* __restrict__ e,
                            const int*   __restrict__ ii,
                            float*       __restrict__ wnorm,
                            int*         __restrict__ rp_out) {
  __shared__ int rp[NJ + 1];
  const int tid = threadIdx.x;
  if (tid == 0) {
    int pos = 0;
    for (int j = 0; j <= NJ; ++j) {
      while (pos < NNZ && ii[pos] < j) ++pos;
      rp[j] = pos;
      rp_out[j] = pos;
    }
  }
  __syncthreads();
  const int c = tid;
  for (int j = 0; j < NJ; ++j) {
    const int k0 = rp[j], k1 = rp[j + 1];
    float m = -1e30f;
    for (int k = k0; k < k1; ++k) m = fmaxf(m, e[c * NNZ + k]);
    float s = 0.0f;
    for (int k = k0; k < k1; ++k) s += expf(e[c * NNZ + k] - m);
    const float inv = 1.0f / s;
    for (int k = k0; k < k1; ++k) wnorm[k * NC + c] = expf(e[c * NNZ + k] - m) * inv;
  }
}

// ---------------------------------------------------------------------------
// Kernel 2: fused bf16-MFMA GEMM + aggregation.
// Block = 4 frames = 68 rows, 256 threads = 4 waves.
// Wave w computes GEMM output cols [64w, 64w+64) of N=256 ([h0 | h1]).
// M covered by 5 16-row tiles {0,16,32,48,52} (last overlaps, no padding).
// x tile and h tile live in LDS as bf16 with XOR swizzle (row&7)<<4.
// ---------------------------------------------------------------------------
__global__ __launch_bounds__(256, 3) void fused_kernel(
    const float* __restrict__ x,
    const float* __restrict__ W,
    const float* __restrict__ wnorm,
    const int*   __restrict__ rp,
    const int*   __restrict__ idxj,
    float*       __restrict__ out) {
  __shared__ __align__(16) short xs[RPB * FD];    // bf16 x tile, swizzled
  __shared__ __align__(16) short hsm[RPB * 256];  // bf16 h tile, swizzled
  __shared__ int rps[NJ + 1];
  __shared__ int jjs[NNZ];

  const int tid  = threadIdx.x;
  const int w    = tid >> 6;
  const int lane = tid & 63;
  const int l15  = lane & 15;
  const int l4   = lane >> 4;
  const int row0 = blockIdx.x * RPB;

  if (tid < NJ + 1) rps[tid] = rp[tid];
  if (tid >= 32 && tid < 32 + NNZ) jjs[tid - 32] = idxj[tid - 32];

  // ---- B fragments: W cols [64w, 64w+64), all K=128, bf16 ----
  // B layout (16x16x32): col = lane&15, k = (lane>>4)*8 + e
  bf16x8 bfrag[4][4];  // [nt][ks]
#pragma unroll
  for (int nt = 0; nt < 4; ++nt) {
    const int n = w * 64 + nt * 16 + l15;
    const float* Wp = W + (size_t)(n >> 7) * (FD * NC) + (n & 127);
#pragma unroll
    for (int ks = 0; ks < 4; ++ks) {
      bf16x8 v;
#pragma unroll
      for (int e = 0; e < 8; ++e)
        v[e] = (short)f2bf(Wp[(size_t)(ks * 32 + l4 * 8 + e) * NC]);
      bfrag[nt][ks] = v;
    }
  }

  // ---- stage x tile -> LDS bf16 (swizzled) ----
  for (int idx = tid; idx < RPB * (FD / 4); idx += 256) {
    const int row = idx >> 5, seg = idx & 31;
    const float4 v = *(const float4*)(x + (size_t)(row0 + row) * FD + seg * 4);
    ushort4 b;
    b.x = f2bf(v.x); b.y = f2bf(v.y); b.z = f2bf(v.z); b.w = f2bf(v.w);
    const int byte = row * 256 + ((seg * 8) ^ ((row & 7) << 4));
    *(ushort4*)((char*)xs + byte) = b;
  }
  __syncthreads();

  // ---- MFMA GEMM over 5 M-tiles ----
  const int m0tab[5] = {0, 16, 32, 48, 52};
#pragma unroll
  for (int m = 0; m < 5; ++m) {
    const int m0 = m0tab[m];
    // A frags: row = m0 + (lane&15), k = (lane>>4)*8 + e  -> ds_read_b128
    const int arow = m0 + l15;
    const int sw = (arow & 7) << 4;
    bf16x8 af[4];
#pragma unroll
    for (int ks = 0; ks < 4; ++ks) {
      const int bir = ((l4 * 16) + ks * 64) ^ sw;
      af[ks] = *(const bf16x8*)((const char*)xs + arow * 256 + bir);
    }
    f32x4 acc[4];
#pragma unroll
    for (int nt = 0; nt < 4; ++nt) acc[nt] = (f32x4){0.f, 0.f, 0.f, 0.f};
#pragma unroll
    for (int ks = 0; ks < 4; ++ks)
#pragma unroll
      for (int nt = 0; nt < 4; ++nt)
        acc[nt] = __builtin_amdgcn_mfma_f32_16x16x32_bf16(af[ks], bfrag[nt][ks],
                                                          acc[nt], 0, 0, 0);
    // store h frags (D layout: col = lane&15, row = (lane>>4)*4 + q)
#pragma unroll
    for (int nt = 0; nt < 4; ++nt) {
      const int n = w * 64 + nt * 16 + l15;
#pragma unroll
      for (int q = 0; q < 4; ++q) {
        const int rr = m0 + l4 * 4 + q;
        if (m < 4 || rr >= 64) {   // overlap tile writes only rows 64..67
          const int byte = rr * 512 + ((n * 2) ^ ((rr & 7) << 4));
          *(short*)((char*)hsm + byte) = (short)f2bf(acc[nt][q]);
        }
      }
    }
  }
  __syncthreads();

  // ---- aggregation: out[r,c] = sum_k wnorm[k,c] * h_{diag?0:1}[nbr,c] ----
  const int cq = tid & 31, c0 = cq * 4;
  for (int r = tid >> 5; r < RPB; r += 8) {
    const int j = r % NJ;
    const int fbase = r - j;           // first row of this frame
    const int k0 = rps[j], k1 = rps[j + 1];
    float4 o = make_float4(0.f, 0.f, 0.f, 0.f);
    for (int k = k0; k < k1; ++k) {
      const int col = jjs[k];
      const float4 wk = *(const float4*)(wnorm + (size_t)k * NC + c0);
      const int hr = fbase + col;
      const int nb = ((col == j ? 0 : 128) + c0) * 2;
      const int byte = hr * 512 + (nb ^ ((hr & 7) << 4));
      const ushort4 hv = *(const ushort4*)((const char*)hsm + byte);
      o.x += wk.x * bf2f(hv.x);
      o.y += wk.y * bf2f(hv.y);
      o.z += wk.z * bf2f(hv.z);
      o.w += wk.w * bf2f(hv.w);
    }
    *(float4*)(out + (size_t)(row0 + r) * NC + c0) = o;
  }
}

// ---------------------------------------------------------------------------
extern "C" void kernel_launch(void* const* d_in, const int* in_sizes, int n_in,
                              void* d_out, int out_size, void* d_ws, size_t ws_size,
                              hipStream_t stream) {
  const float* x  = (const float*)d_in[0];  // [B,T,J,F]
  const float* W  = (const float*)d_in[1];  // [2,F,C]
  const float* e  = (const float*)d_in[2];  // [C,NNZ]
  const int*   ii = (const int*)d_in[3];    // [NNZ]
  const int*   jj = (const int*)d_in[4];    // [NNZ]
  float* out = (float*)d_out;

  float* wnorm = (float*)d_ws;                                   // [NNZ][NC]
  int*   rp    = (int*)((char*)d_ws + NNZ * NC * sizeof(float)); // [NJ+1]

  prep_kernel<<<1, NC, 0, stream>>>(e, ii, wnorm, rp);

  const int frames = in_sizes[0] / (NJ * FD);   // 15552
  const int blocks = frames / FR;               // 3888
  fused_kernel<<<blocks, 256, 0, stream>>>(x, W, wnorm, rp, jj, out);
}

// Round 3
// 143.018 us; speedup vs baseline: 2.2229x; 1.2235x over previous
//
#include <hip/hip_runtime.h>

#define NJ   17
#define FD   128
#define NC   128
#define NNZ  49
#define FR   2            // frames per block
#define RPB  (FR * NJ)    // 34 rows per block

// d_ws layout:
//   [0      .. 65536)  Wpack: bf16 W in MFMA B-frag order [n][kb][8], n<128->W0
//   [65536  .. 90624)  wnorm: f32 [NNZ][NC]
//   [90624  .. 90696)  rp:    int [NJ+1]
#define WS_WNORM 65536
#define WS_RP    90624

typedef __attribute__((ext_vector_type(8))) short bf16x8;   // 8 bf16 (4 VGPR)
typedef __attribute__((ext_vector_type(4))) float f32x4;

__device__ __forceinline__ ushort f2bf(float f) {   // f32 -> bf16 RNE
  unsigned u = __float_as_uint(f);
  u = (u + 0x7fffu + ((u >> 16) & 1u)) >> 16;
  return (ushort)u;
}
__device__ __forceinline__ float bf2f(ushort s) {
  return __uint_as_float(((unsigned)s) << 16);
}

// ---------------------------------------------------------------------------
// Kernel 1a: adjacency softmax prep (validated in rounds 1-2).
// ---------------------------------------------------------------------------
__global__ void prep_kernel(const float* __restrict__ e,
                            const int*   __restrict__ ii,
                            float*       __restrict__ wnorm,
                            int*         __restrict__ rp_out) {
  __shared__ int rp[NJ + 1];
  const int tid = threadIdx.x;
  if (tid == 0) {
    int pos = 0;
    for (int j = 0; j <= NJ; ++j) {
      while (pos < NNZ && ii[pos] < j) ++pos;
      rp[j] = pos;
      rp_out[j] = pos;
    }
  }
  __syncthreads();
  const int c = tid;
  for (int j = 0; j < NJ; ++j) {
    const int k0 = rp[j], k1 = rp[j + 1];
    float m = -1e30f;
    for (int k = k0; k < k1; ++k) m = fmaxf(m, e[c * NNZ + k]);
    float s = 0.0f;
    for (int k = k0; k < k1; ++k) s += expf(e[c * NNZ + k] - m);
    const float inv = 1.0f / s;
    for (int k = k0; k < k1; ++k) wnorm[k * NC + c] = expf(e[c * NNZ + k] - m) * inv;
  }
}

// ---------------------------------------------------------------------------
// Kernel 1b: pack W (f32 [2][128][128]) -> bf16 B-fragment layout.
// Wpack flat bf16 index = n*128 + kb*8 + e  <=>  W[n>>7][kb*8+e][n&127].
// 4096 threads, one 16B chunk each.
// ---------------------------------------------------------------------------
__global__ void pack_kernel(const float* __restrict__ W,
                            bf16x8* __restrict__ Wpack) {
  const int idx = blockIdx.x * 256 + threadIdx.x;   // [0, 4096)
  const int n  = idx >> 4;
  const int kb = idx & 15;
  const float* Wp = W + (size_t)(n >> 7) * (FD * NC) + (n & 127);
  bf16x8 v;
#pragma unroll
  for (int e = 0; e < 8; ++e)
    v[e] = (short)f2bf(Wp[(size_t)(kb * 8 + e) * NC]);
  Wpack[idx] = v;
}

// ---------------------------------------------------------------------------
// Kernel 2: fused bf16-MFMA GEMM + aggregation.
// Block = 2 frames = 34 rows, 256 threads = 4 waves.
// Wave w computes GEMM output cols [64w, 64w+64) of N=256 ([h0 | h1]).
// M covered by 3 16-row tiles {0,16,18} (last overlaps; writes rows>=32 only).
// x tile and h tile in LDS as bf16, XOR-swizzled (row&7)<<4.
// ---------------------------------------------------------------------------
__global__ __launch_bounds__(256, 4) void fused_kernel(
    const float* __restrict__ x,
    const bf16x8* __restrict__ Wpack,
    const float* __restrict__ wnorm,
    const int*   __restrict__ rp,
    const int*   __restrict__ idxj,
    float*       __restrict__ out) {
  __shared__ __align__(16) short xs[RPB * FD];    // bf16 x tile, swizzled (8.5 KB)
  __shared__ __align__(16) short hsm[RPB * 256];  // bf16 h tile, swizzled (17 KB)
  __shared__ int rps[NJ + 1];
  __shared__ int jjs[NNZ];

  const int tid  = threadIdx.x;
  const int w    = tid >> 6;
  const int lane = tid & 63;
  const int l15  = lane & 15;
  const int l4   = lane >> 4;
  const int row0 = blockIdx.x * RPB;

  if (tid < NJ + 1) rps[tid] = rp[tid];
  if (tid >= 32 && tid < 32 + NNZ) jjs[tid - 32] = idxj[tid - 32];

  // ---- stage x tile -> LDS bf16 (swizzled), coalesced float4 reads ----
  for (int idx = tid; idx < RPB * (FD / 4); idx += 256) {
    const int row = idx >> 5, seg = idx & 31;
    const float4 v = *(const float4*)(x + (size_t)(row0 + row) * FD + seg * 4);
    ushort4 b;
    b.x = f2bf(v.x); b.y = f2bf(v.y); b.z = f2bf(v.z); b.w = f2bf(v.w);
    const int byte = row * 256 + ((seg * 8) ^ ((row & 7) << 4));
    *(ushort4*)((char*)xs + byte) = b;
  }
  __syncthreads();

  // ---- A frags for all 3 M-tiles (ds_read_b128, swizzled) ----
  const int m0tab[3] = {0, 16, 18};
  bf16x8 af[3][4];   // [m][ks]
#pragma unroll
  for (int m = 0; m < 3; ++m) {
    const int arow = m0tab[m] + l15;
    const int sw = (arow & 7) << 4;
#pragma unroll
    for (int ks = 0; ks < 4; ++ks) {
      const int bir = ((l4 * 16) + ks * 64) ^ sw;
      af[m][ks] = *(const bf16x8*)((const char*)xs + arow * 256 + bir);
    }
  }

  // ---- GEMM: nt outer (only 4 B-frags live), m inner ----
#pragma unroll
  for (int nt = 0; nt < 4; ++nt) {
    const int n = w * 64 + nt * 16 + l15;
    bf16x8 bf[4];
#pragma unroll
    for (int ks = 0; ks < 4; ++ks)
      bf[ks] = Wpack[n * 16 + ks * 4 + l4];

    f32x4 acc[3];
#pragma unroll
    for (int m = 0; m < 3; ++m) acc[m] = (f32x4){0.f, 0.f, 0.f, 0.f};
#pragma unroll
    for (int ks = 0; ks < 4; ++ks)
#pragma unroll
      for (int m = 0; m < 3; ++m)
        acc[m] = __builtin_amdgcn_mfma_f32_16x16x32_bf16(af[m][ks], bf[ks],
                                                         acc[m], 0, 0, 0);
    // store h frags (D layout: col = lane&15, row = (lane>>4)*4 + q)
#pragma unroll
    for (int m = 0; m < 3; ++m) {
      const int m0 = m0tab[m];
#pragma unroll
      for (int q = 0; q < 4; ++q) {
        const int rr = m0 + l4 * 4 + q;
        if (m < 2 || rr >= 32) {   // overlap tile writes only rows 32..33
          const int byte = rr * 512 + ((n * 2) ^ ((rr & 7) << 4));
          *(short*)((char*)hsm + byte) = (short)f2bf(acc[m][q]);
        }
      }
    }
  }
  __syncthreads();

  // ---- aggregation: out[r,c] = sum_k wnorm[k,c] * h_{diag?0:1}[nbr,c] ----
  const int cq = tid & 31, c0 = cq * 4;
  for (int r = tid >> 5; r < RPB; r += 8) {
    const int j = (r >= NJ) ? r - NJ : r;
    const int fbase = r - j;           // first row of this frame (0 or 17)
    const int k0 = rps[j], k1 = rps[j + 1];
    float4 o = make_float4(0.f, 0.f, 0.f, 0.f);
    for (int k = k0; k < k1; ++k) {
      const int col = jjs[k];
      const float4 wk = *(const float4*)(wnorm + (size_t)k * NC + c0);
      const int hr = fbase + col;
      const int nb = ((col == j ? 0 : 128) + c0) * 2;
      const int byte = hr * 512 + (nb ^ ((hr & 7) << 4));
      const ushort4 hv = *(const ushort4*)((const char*)hsm + byte);
      o.x += wk.x * bf2f(hv.x);
      o.y += wk.y * bf2f(hv.y);
      o.z += wk.z * bf2f(hv.z);
      o.w += wk.w * bf2f(hv.w);
    }
    *(float4*)(out + (size_t)(row0 + r) * NC + c0) = o;
  }
}

// ---------------------------------------------------------------------------
extern "C" void kernel_launch(void* const* d_in, const int* in_sizes, int n_in,
                              void* d_out, int out_size, void* d_ws, size_t ws_size,
                              hipStream_t stream) {
  const float* x  = (const float*)d_in[0];  // [B,T,J,F]
  const float* W  = (const float*)d_in[1];  // [2,F,C]
  const float* e  = (const float*)d_in[2];  // [C,NNZ]
  const int*   ii = (const int*)d_in[3];    // [NNZ]
  const int*   jj = (const int*)d_in[4];    // [NNZ]
  float* out = (float*)d_out;

  bf16x8* Wpack = (bf16x8*)d_ws;
  float*  wnorm = (float*)((char*)d_ws + WS_WNORM);
  int*    rp    = (int*)((char*)d_ws + WS_RP);

  prep_kernel<<<1, NC, 0, stream>>>(e, ii, wnorm, rp);
  pack_kernel<<<16, 256, 0, stream>>>((const float*)d_in[1], Wpack);

  const int frames = in_sizes[0] / (NJ * FD);   // 15552
  const int blocks = frames / FR;               // 7776
  fused_kernel<<<blocks, 256, 0, stream>>>(x, Wpack, wnorm, rp, jj, out);
}